// Round 7
// baseline (3085.319 us; speedup 1.0000x reference)
//
#include <hip/hip_runtime.h>
#include <type_traits>
#include <utility>

// Problem constants: T=2048, B=256, F=64, H=256, O=1
#define T_STEPS 2048
#define BATCH   256
#define FEAT    64
#define HID     256
#define KAUG    320   // FEAT + HID
#define NTHR    1024  // threads per block = 16 waves = 4 waves/EU
#define NW      16    // waves per block
#define KCH     20    // KAUG / NW -> 80 weight floats = 20 v4f chunks per lane

// R4-R6 evidence: the backend's pressure heuristics sink/remat the invariant
// weight loads into the t-loop (VGPR_Count pinned at 60, in-loop L2 reloads,
// VALUBusy 42%) and IGNORE waves_per_eu(4,4) AND a 84KB LDS occupancy cap.
// Fix: launder the 80 weight values through an empty asm volatile("+v") INSIDE
// the loop. They become loop-carried asm outputs: opaque (non-remat-able),
// forcibly live across the backedge. With unavoidable pressure ~110, the
// scheduler must concede occupancy to 4 waves/EU (the LDS pad already caps it
// there) and grant ~128 VGPRs. Failure signature if RA spills instead:
// WRITE_SIZE explodes -> watch it.
// Accuracy note (R6 calibration): per-step error is amplified ~2000-4000x by
// the recurrence (fp32 absmax 3.9e-3 from ~1e-6/step). fp16/bf16/MFMA paths
// would inject ~3e-4/step -> absmax ~1 >> 3.16e-2 threshold. Must stay fp32.

typedef float v4f __attribute__((ext_vector_type(4)));

template <int N>
struct Unroll {
    template <typename F>
    __device__ __forceinline__ static void run(F&& f) {
        Unroll<N - 1>::run(f);
        f(std::integral_constant<int, N - 1>{});
    }
};
template <>
struct Unroll<0> {
    template <typename F>
    __device__ __forceinline__ static void run(F&&) {}
};

// fast tanh: tanh(z) = 1 - 2/(exp(2z)+1). Saturates correctly at +/-inf.
__device__ __forceinline__ float fast_tanh(float z) {
    float e = __expf(2.0f * z);
    return 1.0f - 2.0f * __builtin_amdgcn_rcpf(e + 1.0f);
}

// One block per batch element (grid 256 = CU count, 1 block/CU).
// Wave w owns k-range [20w, 20w+20) of a=[x_t; h]; lane l owns neurons 4l..4l+3.
__global__
__attribute__((amdgpu_flat_work_group_size(NTHR, NTHR), amdgpu_waves_per_eu(4, 4)))
void rnn_kernel(const float* __restrict__ x,    // (T, B, F)
                const float* __restrict__ W0,   // (H, F+H) row-major
                const float* __restrict__ b0,   // (H)
                const float* __restrict__ Wfc,  // (1, H)
                const float* __restrict__ bfc,  // (1)
                float* __restrict__ out)        // (B, T)
{
    const int b    = blockIdx.x;
    const int tid  = threadIdx.x;
    const int w    = tid >> 6;
    const int lane = tid & 63;
    const int kbase = KCH * w;

    __shared__ float a_buf[2][KAUG];      // double-buffered augmented input (2.5 KB)
    __shared__ float part[NW][HID];       // per-wave partial sums (16 KB)
    __shared__ float out_buf[T_STEPS];    // per-step outputs (8 KB)
    // Occupancy limiter: total LDS = 83968 B > 81920 B -> 1 WG/CU -> 128-VGPR cap.
    __shared__ float lds_pad[14208];
    if (blockIdx.x == 0xFFFFFFFFu) {      // never taken; keeps lds_pad alive
        ((volatile float*)lds_pad)[tid] = 1.0f;
    }

    // wch[n][c] = W0 row (4*lane+n), k-span [kbase+4c, kbase+4c+4)  (natural
    // layout: one v4f global load each, no transpose). 20 v4f = 80 VGPRs.
    v4f wch[4][KCH / 4];
    Unroll<4>::run([&](auto n) {
        const float* w0p = W0 + (4 * lane + n.value) * KAUG + kbase;
        Unroll<KCH / 4>::run([&](auto c) {
            wch[n.value][c.value] = *reinterpret_cast<const v4f*>(w0p + 4 * c.value);
        });
    });

    float b0_r = 0.0f, wfc_r = 0.0f;
    if (tid < HID) { b0_r = b0[tid]; wfc_r = Wfc[tid]; }
    const float bfc_r = bfc[0];

    // prologue: a_buf[0] = [x_0 ; h0=0]; out_buf[t] = bfc
    if (tid < FEAT) a_buf[0][tid] = x[b * FEAT + tid];
    if (tid < HID)  a_buf[0][FEAT + tid] = 0.0f;
    out_buf[tid]        = bfc_r;
    out_buf[tid + NTHR] = bfc_r;
    __syncthreads();

    for (int t = 0; t < T_STEPS; ++t) {
        const int cur = t & 1;
        const int nxt = cur ^ 1;

        // ---- register pin: opaque redefinition of all 20 weight chunks.
        // Zero instructions; makes the weights loop-carried, non-remat-able.
        asm volatile("" : "+v"(wch[0][0]), "+v"(wch[0][1]), "+v"(wch[0][2]),
                          "+v"(wch[0][3]), "+v"(wch[0][4]));
        asm volatile("" : "+v"(wch[1][0]), "+v"(wch[1][1]), "+v"(wch[1][2]),
                          "+v"(wch[1][3]), "+v"(wch[1][4]));
        asm volatile("" : "+v"(wch[2][0]), "+v"(wch[2][1]), "+v"(wch[2][2]),
                          "+v"(wch[2][3]), "+v"(wch[2][4]));
        asm volatile("" : "+v"(wch[3][0]), "+v"(wch[3][1]), "+v"(wch[3][2]),
                          "+v"(wch[3][3]), "+v"(wch[3][4]));

        // prefetch x for step t+1 (hidden under FMA phase)
        float xnext = 0.0f;
        if (tid < FEAT) {
            int tn = (t + 1 < T_STEPS) ? (t + 1) : t;
            xnext = x[tn * (BATCH * FEAT) + b * FEAT + tid];
        }

        // ---- FMA phase: 80 fp32 FMAs/lane, 4 independent acc chains,
        // fed by 5 uniform-address ds_read_b128 broadcasts (conflict-free)
        float acc[4] = {0.f, 0.f, 0.f, 0.f};
        const v4f* a4 = reinterpret_cast<const v4f*>(&a_buf[cur][kbase]);
        Unroll<KCH / 4>::run([&](auto c) {
            const v4f av = a4[c.value];
            Unroll<4>::run([&](auto n) {
                const v4f wv = wch[n.value][c.value];
                acc[n.value] = fmaf(wv.x, av.x, acc[n.value]);
                acc[n.value] = fmaf(wv.y, av.y, acc[n.value]);
                acc[n.value] = fmaf(wv.z, av.z, acc[n.value]);
                acc[n.value] = fmaf(wv.w, av.w, acc[n.value]);
            });
        });

        // partials: contiguous b128 store, conflict-free
        *reinterpret_cast<v4f*>(&part[w][4 * lane]) =
            (v4f){acc[0], acc[1], acc[2], acc[3]};
        __syncthreads();

        // ---- reduce phase: waves 0-3, thread tid owns neuron tid
        if (tid < HID) {
            float s = b0_r;
            Unroll<NW>::run([&](auto ww) { s += part[ww.value][tid]; });
            float h = fast_tanh(s);
            a_buf[nxt][FEAT + tid] = h;
            if (tid < FEAT) a_buf[nxt][tid] = xnext;

            // out[b][t] = Wfc . h + bfc : wave shuffle reduce + one LDS atomic
            float p = wfc_r * h;
#pragma unroll
            for (int m = 32; m >= 1; m >>= 1) p += __shfl_xor(p, m, 64);
            if (lane == 0) atomicAdd(&out_buf[t], p);
        }
        __syncthreads();   // a_buf[nxt] + out_buf[t] settled before reuse
    }

    // epilogue: coalesced float2 store of the block's 2048 outputs
    float2* o2 = reinterpret_cast<float2*>(out + b * T_STEPS);
    const float2* s2 = reinterpret_cast<const float2*>(out_buf);
    o2[tid] = s2[tid];
}

extern "C" void kernel_launch(void* const* d_in, const int* in_sizes, int n_in,
                              void* d_out, int out_size, void* d_ws, size_t ws_size,
                              hipStream_t stream) {
    const float* x   = (const float*)d_in[0];
    const float* W0  = (const float*)d_in[1];
    const float* b0  = (const float*)d_in[2];
    const float* Wfc = (const float*)d_in[3];
    const float* bfc = (const float*)d_in[4];
    // d_in[5] = feature_n == 0 -> no autoregressive tail
    float* out = (float*)d_out;

    rnn_kernel<<<dim3(BATCH), dim3(NTHR), 0, stream>>>(x, W0, b0, Wfc, bfc, out);
}